// Round 8
// baseline (224.390 us; speedup 1.0000x reference)
//
#include <hip/hip_runtime.h>
#include <math.h>

#define SL 1024      // sequence length (H*W)
#define CH 384       // channels
#define NHEAD 8
#define DH 48        // head dim (dk == dv)
#define NBIAS 3969
#define NTOK 8192    // B * SL
#define BATCH 8
#define CFF 1536
#define LN_EPS 1e-5f
#define QKVLD 1152
#define HMS 3145728  // shorts per head-major tensor: B*NH*SL*48

// bf16 weight pool layout (element offsets)
#define WQKV_OFF 0
#define WO_OFF   442368
#define F1_OFF   589824
#define F2_OFF   1179648
#define WTOT     1769472

typedef float floatx4 __attribute__((ext_vector_type(4)));
typedef short bf16x8 __attribute__((ext_vector_type(8)));

__device__ __forceinline__ unsigned f2bf_u(float f) {
  unsigned u = __float_as_uint(f);
  return (u + 0x7fffu + ((u >> 16) & 1u)) >> 16;
}
__device__ __forceinline__ unsigned pack2(float a, float b) {
  return f2bf_u(a) | (f2bf_u(b) << 16);
}

// async global->LDS, 16B per lane; lds base must be wave-uniform
__device__ __forceinline__ void gload_lds16(const void* g, void* l) {
  __builtin_amdgcn_global_load_lds(
      (const __attribute__((address_space(1))) void*)g,
      (__attribute__((address_space(3))) void*)l, 16, 0, 0);
}

// ---------------- weights fp32 -> bf16 pool ----------------
__global__ void k_w2bf(const float* __restrict__ Wq, const float* __restrict__ Wk,
                       const float* __restrict__ Wv, const float* __restrict__ Wo,
                       const float* __restrict__ f1, const float* __restrict__ f2,
                       short* __restrict__ dst) {
  size_t i = ((size_t)blockIdx.x * 256 + threadIdx.x) * 8;
  if (i >= WTOT) return;
  const float* s;
  size_t base;
  if (i < 147456)        { s = Wq; base = 0; }
  else if (i < 294912)   { s = Wk; base = 147456; }
  else if (i < WO_OFF)   { s = Wv; base = 294912; }
  else if (i < F1_OFF)   { s = Wo; base = WO_OFF; }
  else if (i < F2_OFF)   { s = f1; base = F1_OFF; }
  else                   { s = f2; base = F2_OFF; }
  const float4* p = (const float4*)(s + (i - base));
  float4 a = p[0], b = p[1];
  uint4 o;
  o.x = pack2(a.x, a.y); o.y = pack2(a.z, a.w);
  o.z = pack2(b.x, b.y); o.w = pack2(b.z, b.w);
  *(uint4*)(dst + i) = o;
}

// ---------------- fused transpose + LayerNorm: x (B,C,L) -> tok_bf (B*L, C) ----
__global__ __launch_bounds__(256) void k_ln_fused(
    const float* __restrict__ x, const float* __restrict__ gamma,
    const float* __restrict__ beta, short* __restrict__ tok) {
  __shared__ float sx[32][385];  // [l][c]
  int b = blockIdx.y, l0 = blockIdx.x * 32;
  int tid = threadIdx.x;
  const float* xb = x + (size_t)b * CH * SL;
  int cr = tid >> 3, ls = (tid & 7) * 4;
#pragma unroll
  for (int c0 = 0; c0 < CH; c0 += 32) {
    int c = c0 + cr;
    float4 v = *(const float4*)(xb + (size_t)c * SL + l0 + ls);
    sx[ls + 0][c] = v.x; sx[ls + 1][c] = v.y;
    sx[ls + 2][c] = v.z; sx[ls + 3][c] = v.w;
  }
  __syncthreads();
  int tl = tid >> 3, p = tid & 7;  // 8 threads per token, 48 channels each
  float vals[48];
  float s = 0.f, q = 0.f;
#pragma unroll
  for (int i = 0; i < 48; i++) {
    float v = sx[tl][p * 48 + i];
    vals[i] = v; s += v; q += v * v;
  }
  s += __shfl_xor(s, 1, 64); q += __shfl_xor(q, 1, 64);
  s += __shfl_xor(s, 2, 64); q += __shfl_xor(q, 2, 64);
  s += __shfl_xor(s, 4, 64); q += __shfl_xor(q, 4, 64);
  float mu = s * (1.0f / CH);
  float rstd = rsqrtf(q * (1.0f / CH) - mu * mu + LN_EPS);
  short* orow = tok + (size_t)(b * SL + l0 + tl) * CH + p * 48;
#pragma unroll
  for (int i = 0; i < 48; i += 2) {
    float a = (vals[i] - mu) * rstd * gamma[p * 48 + i] + beta[p * 48 + i];
    float c = (vals[i + 1] - mu) * rstd * gamma[p * 48 + i + 1] + beta[p * 48 + i + 1];
    *(unsigned*)(orow + i) = pack2(a, c);
  }
}

// ---------------- bf16 MFMA GEMM: C(M,N) = A(M,K) @ W(N,K)^T ----------------
// Tile BMx128, BK=64. 256 thr = 4 waves 2x2; wave-tile (BM/2)x64.
// RES_MODE: 0 none, 1 row-major fp32, 2 x-layout (B,C,L) fp32.
// OUT_MODE bits: 1 f32 row-major Cf, 2 bf16 Cb, 4 f32 (B,C,L) Ct,
//                8 bf16 head-major qkv split (Chm: q|k|v each HMS shorts).
template <int BM, bool GELU, bool HAS_BIAS, int RES_MODE, int OUT_MODE>
__global__ __launch_bounds__(256) void k_gemm_mfma(
    const short* __restrict__ A, const short* __restrict__ W,
    const float* __restrict__ bias, const float* __restrict__ res,
    float* __restrict__ Cf, short* __restrict__ Cb, float* __restrict__ Ct,
    short* __restrict__ Chm, int N, int K) {
  constexpr int MI = BM / 32;
  constexpr int ASI = BM * 2 / 64;
  __shared__ short As[BM * 64];
  __shared__ short Bs[128 * 64];
  int tid = threadIdx.x;
  int wid = tid >> 6, lane = tid & 63;
  int lanelo = lane & 15, quad = lane >> 4;
  int wm = wid & 1, wn = wid >> 1;
  int m0 = blockIdx.y * BM, n0 = blockIdx.x * 128;

  const short* Aga[ASI];
  short* Ala[ASI];
#pragma unroll
  for (int s = 0; s < ASI; s++) {
    int p = wid * (BM * 2) + s * 64 + lane;
    int row = p >> 3, ch = (p & 7) ^ (row & 7);
    Aga[s] = A + (size_t)(m0 + row) * K + ch * 8;
    Ala[s] = As + (wid * (BM * 2) + s * 64) * 8;
  }
  const short* Bga[4];
  short* Bla[4];
#pragma unroll
  for (int s = 0; s < 4; s++) {
    int p = wid * 256 + s * 64 + lane;
    int row = p >> 3, ch = (p & 7) ^ (row & 7);
    Bga[s] = W + (size_t)(n0 + row) * K + ch * 8;
    Bla[s] = Bs + (wid * 256 + s * 64) * 8;
  }

  floatx4 acc[MI][4];
#pragma unroll
  for (int i = 0; i < MI; i++)
#pragma unroll
    for (int j = 0; j < 4; j++) acc[i][j] = {0.f, 0.f, 0.f, 0.f};

  int x8 = lanelo & 7;
  int ca0 = (quad ^ x8) * 8;
  int ca1 = ((quad + 4) ^ x8) * 8;

  for (int k0 = 0; k0 < K; k0 += 64) {
    __syncthreads();
#pragma unroll
    for (int s = 0; s < ASI; s++) gload_lds16(Aga[s] + k0, Ala[s]);
#pragma unroll
    for (int s = 0; s < 4; s++) gload_lds16(Bga[s] + k0, Bla[s]);
    __syncthreads();
#pragma unroll
    for (int h = 0; h < 2; h++) {
      int co = h ? ca1 : ca0;
      bf16x8 af[MI], bq[4];
#pragma unroll
      for (int i = 0; i < MI; i++)
        af[i] = *(const bf16x8*)&As[(wm * (BM / 2) + i * 16 + lanelo) * 64 + co];
#pragma unroll
      for (int j = 0; j < 4; j++)
        bq[j] = *(const bf16x8*)&Bs[(wn * 64 + j * 16 + lanelo) * 64 + co];
#pragma unroll
      for (int i = 0; i < MI; i++)
#pragma unroll
        for (int j = 0; j < 4; j++)
          acc[i][j] = __builtin_amdgcn_mfma_f32_16x16x32_bf16(af[i], bq[j], acc[i][j], 0, 0, 0);
    }
  }

  // epilogue: C/D row=(lane>>4)*4+reg, col=lane&15; reg = 4 consecutive tokens.
  int colb = n0 + wn * 64 + lanelo;
  float bvv[4];
#pragma unroll
  for (int j = 0; j < 4; j++) bvv[j] = HAS_BIAS ? bias[colb + j * 16] : 0.0f;
#pragma unroll
  for (int i = 0; i < MI; i++) {
    int r = m0 + wm * (BM / 2) + i * 16 + quad * 4;
    int bb = r >> 10, ll = r & 1023;
#pragma unroll
    for (int j = 0; j < 4; j++) {
      int c = colb + j * 16;
      float4 rv = {0.f, 0.f, 0.f, 0.f};
      if (RES_MODE == 2) rv = *(const float4*)(res + ((size_t)bb * CH + c) * SL + ll);
      float vv[4];
#pragma unroll
      for (int reg = 0; reg < 4; reg++) {
        float v = acc[i][j][reg] + bvv[j];
        if (RES_MODE == 1) v += res[(size_t)(r + reg) * N + c];
        if (RES_MODE == 2) v += (&rv.x)[reg];
        if (GELU) v = 0.5f * v * (1.0f + erff(v * 0.7071067811865476f));
        vv[reg] = v;
      }
      if (OUT_MODE & 1) {
#pragma unroll
        for (int reg = 0; reg < 4; reg++) Cf[(size_t)(r + reg) * N + c] = vv[reg];
      }
      if (OUT_MODE & 2) {
#pragma unroll
        for (int reg = 0; reg < 4; reg++) Cb[(size_t)(r + reg) * N + c] = (short)f2bf_u(vv[reg]);
      }
      if (OUT_MODE & 4) {
        float4 ov = {vv[0], vv[1], vv[2], vv[3]};
        *(float4*)(Ct + ((size_t)bb * CH + c) * SL + ll) = ov;
      }
      if (OUT_MODE & 8) {
        int part = c / 384;
        int rem = c - part * 384;
        int hh = rem / 48, dd = rem - hh * 48;
        short* dst = Chm + (size_t)part * HMS +
                     ((size_t)(bb * NHEAD + hh) * SL + ll) * 48 + dd;
#pragma unroll
        for (int reg = 0; reg < 4; reg++) dst[reg * 48] = (short)f2bf_u(vv[reg]);
      }
    }
  }
}

// ---------------- MFMA flash attention, head-major K/V, pipelined staging ----
// qh,kh,vh: (B*NH, SL, 48) bf16. ao: (NTOK, 384) bf16 token-major.
// Block: one (b,h), 128 q-rows, 4 waves x 32 rows. m-tiles of 64 keys.
// Tile t+1 is prefetched into registers during compute of tile t; between the
// two barriers only reg->LDS commits remain (global latency off critical path).
__global__ __launch_bounds__(256) void k_attn_mfma(
    const short* __restrict__ qh, const short* __restrict__ kh,
    const short* __restrict__ vh, const float* __restrict__ rel_bias,
    short* __restrict__ ao) {
  __shared__ short QP[128 * 72];     // Q tile (prologue) / P patches (loop)
  __shared__ short Ks[64 * 72];
  __shared__ short Vts[48 * 72];     // transposed: row=d, col=m

  int b = blockIdx.z, h = blockIdx.y;
  int l0 = blockIdx.x * 128;
  int tid = threadIdx.x;
  int wid = tid >> 6, lane = tid & 63;
  int lanelo = lane & 15, quad = lane >> 4;
  size_t hb = ((size_t)b * NHEAD + h) * SL;
  size_t bSL = (size_t)b * SL;
  const float* rbh = rel_bias + h * NBIAS;
  const short* kbase = kh + hb * 48;
  const short* vbase = vh + hb * 48;

  // ---- stage Q tile (contiguous 12 KB) + zero pads ----
  {
    const short* qsrc = qh + (hb + l0) * 48;
    for (int g = tid; g < 768; g += 256) {
      int row = g / 6, pos = g - row * 6;
      *(uint4*)&QP[row * 72 + pos * 8] = *(const uint4*)(qsrc + g * 8);
    }
  }
  for (int z = tid; z < 128 * 8; z += 256) {
    int r = z >> 3, u = z & 7;
    ((unsigned*)&QP[r * 72 + 48])[u] = 0u;
    if (r < 64) ((unsigned*)&Ks[r * 72 + 48])[u] = 0u;
  }

  // staging assignment (tid < 192): K granules 2t,2t+1; V token-pair+d-group
  int kg = 2 * tid;
  int krow = kg / 6, kpos = kg - krow * 6;
  int vmp = tid & 31, vdg = tid >> 5;

  // ---- prefetch tile 0 ----
  uint4 kr0, kr1, vr0, vr1;
  if (tid < 192) {
    kr0 = *(const uint4*)(kbase + kg * 8);
    kr1 = *(const uint4*)(kbase + kg * 8 + 8);
    const short* vs = vbase + (2 * vmp) * 48 + vdg * 8;
    vr0 = *(const uint4*)vs;
    vr1 = *(const uint4*)(vs + 48);
  }
  __syncthreads();  // Q tile + pads visible

  // resident Q A-fragments: [i][khalf]
  bf16x8 aq[2][2];
#pragma unroll
  for (int i = 0; i < 2; i++) {
    aq[i][0] = *(const bf16x8*)&QP[(wid * 32 + i * 16 + lanelo) * 72 + quad * 8];
    aq[i][1] = *(const bf16x8*)&QP[(wid * 32 + i * 16 + lanelo) * 72 + 32 + quad * 8];
  }

  floatx4 O[2][3];
#pragma unroll
  for (int i = 0; i < 2; i++)
#pragma unroll
    for (int d = 0; d < 3; d++) O[i][d] = {0.f, 0.f, 0.f, 0.f};
  float lsum[2][4] = {{0.f, 0.f, 0.f, 0.f}, {0.f, 0.f, 0.f, 0.f}};
  int boff[2];
#pragma unroll
  for (int i = 0; i < 2; i++)
    boff[i] = 1056 - (l0 + wid * 32 + i * 16 + quad * 4) + lanelo;

  short* Pw = &QP[wid * 32 * 72];

  for (int mt = 0; mt < SL; mt += 64) {
    __syncthreads();  // previous tile's LDS readers done
    if (tid < 192) {  // commit prefetched tile (LDS only -- fast)
      *(uint4*)&Ks[krow * 72 + kpos * 8] = kr0;
      *(uint4*)&Ks[krow * 72 + (kpos + 1) * 8] = kr1;
      union { uint4 u; unsigned short s[8]; } va, vb;
      va.u = vr0; vb.u = vr1;
#pragma unroll
      for (int i = 0; i < 8; i++) {
        unsigned pk = (unsigned)va.s[i] | ((unsigned)vb.s[i] << 16);
        *(unsigned*)&Vts[(vdg * 8 + i) * 72 + 2 * vmp] = pk;
      }
    }
    __syncthreads();  // tile visible
    if (mt + 64 < SL && tid < 192) {  // prefetch next tile (overlaps compute)
      const short* ks = kbase + (size_t)(mt + 64) * 48;
      kr0 = *(const uint4*)(ks + kg * 8);
      kr1 = *(const uint4*)(ks + kg * 8 + 8);
      const short* vs = vbase + (size_t)(mt + 64 + 2 * vmp) * 48 + vdg * 8;
      vr0 = *(const uint4*)vs;
      vr1 = *(const uint4*)(vs + 48);
    }

    // K B-fragments (shared across both i)
    bf16x8 kb[4][2];
#pragma unroll
    for (int nt = 0; nt < 4; nt++) {
      kb[nt][0] = *(const bf16x8*)&Ks[(nt * 16 + lanelo) * 72 + quad * 8];
      kb[nt][1] = *(const bf16x8*)&Ks[(nt * 16 + lanelo) * 72 + 32 + quad * 8];
    }

#pragma unroll
    for (int i = 0; i < 2; i++) {
      floatx4 s[4];
#pragma unroll
      for (int nt = 0; nt < 4; nt++) {
        floatx4 a = {0.f, 0.f, 0.f, 0.f};
        a = __builtin_amdgcn_mfma_f32_16x16x32_bf16(aq[i][0], kb[nt][0], a, 0, 0, 0);
        a = __builtin_amdgcn_mfma_f32_16x16x32_bf16(aq[i][1], kb[nt][1], a, 0, 0, 0);
        s[nt] = a;
      }
#pragma unroll
      for (int nt = 0; nt < 4; nt++) {
        int mo = mt + nt * 16;
#pragma unroll
        for (int reg = 0; reg < 4; reg++) {
          float e = __expf(s[nt][reg] + rbh[boff[i] - reg + mo]);
          lsum[i][reg] += e;
          Pw[(i * 16 + quad * 4 + reg) * 72 + nt * 16 + lanelo] = (short)f2bf_u(e);
        }
      }
    }
    __asm__ volatile("s_waitcnt lgkmcnt(0)" ::: "memory");  // wave-local patch
    bf16x8 pa[2][2];
#pragma unroll
    for (int i = 0; i < 2; i++) {
      pa[i][0] = *(const bf16x8*)&Pw[(i * 16 + lanelo) * 72 + quad * 8];
      pa[i][1] = *(const bf16x8*)&Pw[(i * 16 + lanelo) * 72 + 32 + quad * 8];
    }
#pragma unroll
    for (int d = 0; d < 3; d++) {
      bf16x8 v0 = *(const bf16x8*)&Vts[(d * 16 + lanelo) * 72 + quad * 8];
      bf16x8 v1 = *(const bf16x8*)&Vts[(d * 16 + lanelo) * 72 + 32 + quad * 8];
#pragma unroll
      for (int i = 0; i < 2; i++) {
        O[i][d] = __builtin_amdgcn_mfma_f32_16x16x32_bf16(pa[i][0], v0, O[i][d], 0, 0, 0);
        O[i][d] = __builtin_amdgcn_mfma_f32_16x16x32_bf16(pa[i][1], v1, O[i][d], 0, 0, 0);
      }
    }
  }

  // ---- epilogue: row-sum reduce, normalize, store bf16 token-major ----
#pragma unroll
  for (int i = 0; i < 2; i++)
#pragma unroll
    for (int reg = 0; reg < 4; reg++) {
      float s = lsum[i][reg];
      s += __shfl_xor(s, 1, 64);
      s += __shfl_xor(s, 2, 64);
      s += __shfl_xor(s, 4, 64);
      s += __shfl_xor(s, 8, 64);
      float inv = 1.0f / s;
      size_t base =
          (bSL + (size_t)(l0 + wid * 32 + i * 16 + quad * 4 + reg)) * CH + h * DH;
      ao[base + 0 + lanelo]  = (short)f2bf_u(O[i][0][reg] * inv);
      ao[base + 16 + lanelo] = (short)f2bf_u(O[i][1][reg] * inv);
      ao[base + 32 + lanelo] = (short)f2bf_u(O[i][2][reg] * inv);
    }
}

// ---------------- launch ----------------
extern "C" void kernel_launch(void* const* d_in, const int* in_sizes, int n_in,
                              void* d_out, int out_size, void* d_ws, size_t ws_size,
                              hipStream_t stream) {
  const float* x = (const float*)d_in[0];
  const float* gamma = (const float*)d_in[1];
  const float* beta = (const float*)d_in[2];
  const float* Wq = (const float*)d_in[3];
  const float* Wk = (const float*)d_in[4];
  const float* Wv = (const float*)d_in[5];
  const float* Wo = (const float*)d_in[6];
  const float* bo = (const float*)d_in[7];
  const float* rel_bias = (const float*)d_in[8];
  const float* fc1_w = (const float*)d_in[9];
  const float* fc1_b = (const float*)d_in[10];
  const float* fc2_w = (const float*)d_in[11];
  const float* fc2_b = (const float*)d_in[12];
  float* out = (float*)d_out;

  const size_t TOKCH = (size_t)NTOK * CH;
  float* ws_f = (float*)d_ws;
  float* yb = ws_f;                            // fp32 y = x + attn-proj (token-major)
  short* wbf    = (short*)(yb + TOKCH);        // bf16 weight pool
  short* tok_bf = wbf + WTOT;                  // (NTOK, 384)
  short* hm     = tok_bf + TOKCH;              // q|k|v head-major, 3*HMS shorts
  short* ao_bf  = hm + 3 * (size_t)HMS;        // (NTOK, 384)
  short* yb_bf  = ao_bf + TOKCH;               // (NTOK, 384)
  short* h1_bf  = yb_bf + TOKCH;               // (NTOK, 1536)

  k_w2bf<<<WTOT / 8 / 256, 256, 0, stream>>>(Wq, Wk, Wv, Wo, fc1_w, fc2_w, wbf);
  k_ln_fused<<<dim3(SL / 32, BATCH), 256, 0, stream>>>(x, gamma, beta, tok_bf);

  // qkv = tok @ [Wq|Wk|Wv]^T  -> head-major q,k,v
  k_gemm_mfma<128, false, false, 0, 8>
      <<<dim3(QKVLD / 128, NTOK / 128), 256, 0, stream>>>(
          tok_bf, wbf + WQKV_OFF, nullptr, nullptr, nullptr, nullptr, nullptr,
          hm, QKVLD, CH);

  k_attn_mfma<<<dim3(SL / 128, NHEAD, BATCH), 256, 0, stream>>>(
      hm, hm + HMS, hm + 2 * (size_t)HMS, rel_bias, ao_bf);

  // y = x + ao @ Wo^T + bo  (residual from x in (B,C,L)) -> yb fp32 + bf16
  k_gemm_mfma<64, false, true, 2, 3>
      <<<dim3(CH / 128, NTOK / 64), 256, 0, stream>>>(
          ao_bf, wbf + WO_OFF, bo, x, yb, yb_bf, nullptr, nullptr, CH, CH);

  // h1 = gelu(y @ fc1_w^T + fc1_b) -> bf16
  k_gemm_mfma<128, true, true, 0, 2>
      <<<dim3(CFF / 128, NTOK / 128), 256, 0, stream>>>(
          yb_bf, wbf + F1_OFF, fc1_b, nullptr, nullptr, h1_bf, nullptr, nullptr,
          CFF, CH);

  // out(B,C,L) = y + (h1 @ fc2_w^T + fc2_b)   [direct transposed store]
  k_gemm_mfma<64, false, true, 1, 4>
      <<<dim3(CH / 128, NTOK / 64), 256, 0, stream>>>(
          h1_bf, wbf + F2_OFF, fc2_b, yb, nullptr, nullptr, out, nullptr, CH, CFF);
}

// Round 9
// 213.639 us; speedup vs baseline: 1.0503x; 1.0503x over previous
//
#include <hip/hip_runtime.h>
#include <math.h>

#define SL 1024      // sequence length (H*W)
#define CH 384       // channels
#define NHEAD 8
#define DH 48        // head dim (dk == dv)
#define NBIAS 3969
#define NTOK 8192    // B * SL
#define BATCH 8
#define CFF 1536
#define LN_EPS 1e-5f
#define QKVLD 1152
#define HMS 3145728  // shorts per head-major tensor: B*NH*SL*48

// bf16 weight pool layout (element offsets)
#define WQKV_OFF 0
#define WO_OFF   442368
#define F1_OFF   589824
#define F2_OFF   1179648
#define WTOT     1769472

typedef float floatx4 __attribute__((ext_vector_type(4)));
typedef short bf16x8 __attribute__((ext_vector_type(8)));

__device__ __forceinline__ unsigned f2bf_u(float f) {
  unsigned u = __float_as_uint(f);
  return (u + 0x7fffu + ((u >> 16) & 1u)) >> 16;
}
__device__ __forceinline__ unsigned pack2(float a, float b) {
  return f2bf_u(a) | (f2bf_u(b) << 16);
}

// async global->LDS, 16B per lane; lds base must be wave-uniform
__device__ __forceinline__ void gload_lds16(const void* g, void* l) {
  __builtin_amdgcn_global_load_lds(
      (const __attribute__((address_space(1))) void*)g,
      (__attribute__((address_space(3))) void*)l, 16, 0, 0);
}

// ---------------- weights fp32 -> bf16 pool ----------------
__global__ void k_w2bf(const float* __restrict__ Wq, const float* __restrict__ Wk,
                       const float* __restrict__ Wv, const float* __restrict__ Wo,
                       const float* __restrict__ f1, const float* __restrict__ f2,
                       short* __restrict__ dst) {
  size_t i = ((size_t)blockIdx.x * 256 + threadIdx.x) * 8;
  if (i >= WTOT) return;
  const float* s;
  size_t base;
  if (i < 147456)        { s = Wq; base = 0; }
  else if (i < 294912)   { s = Wk; base = 147456; }
  else if (i < WO_OFF)   { s = Wv; base = 294912; }
  else if (i < F1_OFF)   { s = Wo; base = WO_OFF; }
  else if (i < F2_OFF)   { s = f1; base = F1_OFF; }
  else                   { s = f2; base = F2_OFF; }
  const float4* p = (const float4*)(s + (i - base));
  float4 a = p[0], b = p[1];
  uint4 o;
  o.x = pack2(a.x, a.y); o.y = pack2(a.z, a.w);
  o.z = pack2(b.x, b.y); o.w = pack2(b.z, b.w);
  *(uint4*)(dst + i) = o;
}

// ---------------- fused transpose + LayerNorm: x (B,C,L) -> tok_bf (B*L, C) ----
__global__ __launch_bounds__(256) void k_ln_fused(
    const float* __restrict__ x, const float* __restrict__ gamma,
    const float* __restrict__ beta, short* __restrict__ tok) {
  __shared__ float sx[32][385];  // [l][c]
  int b = blockIdx.y, l0 = blockIdx.x * 32;
  int tid = threadIdx.x;
  const float* xb = x + (size_t)b * CH * SL;
  int cr = tid >> 3, ls = (tid & 7) * 4;
#pragma unroll
  for (int c0 = 0; c0 < CH; c0 += 32) {
    int c = c0 + cr;
    float4 v = *(const float4*)(xb + (size_t)c * SL + l0 + ls);
    sx[ls + 0][c] = v.x; sx[ls + 1][c] = v.y;
    sx[ls + 2][c] = v.z; sx[ls + 3][c] = v.w;
  }
  __syncthreads();
  int tl = tid >> 3, p = tid & 7;  // 8 threads per token, 48 channels each
  float vals[48];
  float s = 0.f, q = 0.f;
#pragma unroll
  for (int i = 0; i < 48; i++) {
    float v = sx[tl][p * 48 + i];
    vals[i] = v; s += v; q += v * v;
  }
  s += __shfl_xor(s, 1, 64); q += __shfl_xor(q, 1, 64);
  s += __shfl_xor(s, 2, 64); q += __shfl_xor(q, 2, 64);
  s += __shfl_xor(s, 4, 64); q += __shfl_xor(q, 4, 64);
  float mu = s * (1.0f / CH);
  float rstd = rsqrtf(q * (1.0f / CH) - mu * mu + LN_EPS);
  short* orow = tok + (size_t)(b * SL + l0 + tl) * CH + p * 48;
#pragma unroll
  for (int i = 0; i < 48; i += 2) {
    float a = (vals[i] - mu) * rstd * gamma[p * 48 + i] + beta[p * 48 + i];
    float c = (vals[i + 1] - mu) * rstd * gamma[p * 48 + i + 1] + beta[p * 48 + i + 1];
    *(unsigned*)(orow + i) = pack2(a, c);
  }
}

// ---------------- bf16 MFMA GEMM: C(M,N) = A(M,K) @ W(N,K)^T ----------------
// Tile BMx128, BK=64. 256 thr = 4 waves 2x2; wave-tile (BM/2)x64.
// RES_MODE: 0 none, 1 row-major fp32, 2 x-layout (B,C,L) fp32.
// OUT_MODE bits: 1 f32 row-major Cf, 2 bf16 Cb, 4 f32 (B,C,L) Ct,
//                8 bf16 head-major qkv split (Chm: q|k|v each HMS shorts).
template <int BM, bool GELU, bool HAS_BIAS, int RES_MODE, int OUT_MODE>
__global__ __launch_bounds__(256) void k_gemm_mfma(
    const short* __restrict__ A, const short* __restrict__ W,
    const float* __restrict__ bias, const float* __restrict__ res,
    float* __restrict__ Cf, short* __restrict__ Cb, float* __restrict__ Ct,
    short* __restrict__ Chm, int N, int K) {
  constexpr int MI = BM / 32;
  constexpr int ASI = BM * 2 / 64;
  __shared__ short As[BM * 64];
  __shared__ short Bs[128 * 64];
  int tid = threadIdx.x;
  int wid = tid >> 6, lane = tid & 63;
  int lanelo = lane & 15, quad = lane >> 4;
  int wm = wid & 1, wn = wid >> 1;
  int m0 = blockIdx.y * BM, n0 = blockIdx.x * 128;

  const short* Aga[ASI];
  short* Ala[ASI];
#pragma unroll
  for (int s = 0; s < ASI; s++) {
    int p = wid * (BM * 2) + s * 64 + lane;
    int row = p >> 3, ch = (p & 7) ^ (row & 7);
    Aga[s] = A + (size_t)(m0 + row) * K + ch * 8;
    Ala[s] = As + (wid * (BM * 2) + s * 64) * 8;
  }
  const short* Bga[4];
  short* Bla[4];
#pragma unroll
  for (int s = 0; s < 4; s++) {
    int p = wid * 256 + s * 64 + lane;
    int row = p >> 3, ch = (p & 7) ^ (row & 7);
    Bga[s] = W + (size_t)(n0 + row) * K + ch * 8;
    Bla[s] = Bs + (wid * 256 + s * 64) * 8;
  }

  floatx4 acc[MI][4];
#pragma unroll
  for (int i = 0; i < MI; i++)
#pragma unroll
    for (int j = 0; j < 4; j++) acc[i][j] = {0.f, 0.f, 0.f, 0.f};

  int x8 = lanelo & 7;
  int ca0 = (quad ^ x8) * 8;
  int ca1 = ((quad + 4) ^ x8) * 8;

  for (int k0 = 0; k0 < K; k0 += 64) {
    __syncthreads();
#pragma unroll
    for (int s = 0; s < ASI; s++) gload_lds16(Aga[s] + k0, Ala[s]);
#pragma unroll
    for (int s = 0; s < 4; s++) gload_lds16(Bga[s] + k0, Bla[s]);
    __syncthreads();
#pragma unroll
    for (int h = 0; h < 2; h++) {
      int co = h ? ca1 : ca0;
      bf16x8 af[MI], bq[4];
#pragma unroll
      for (int i = 0; i < MI; i++)
        af[i] = *(const bf16x8*)&As[(wm * (BM / 2) + i * 16 + lanelo) * 64 + co];
#pragma unroll
      for (int j = 0; j < 4; j++)
        bq[j] = *(const bf16x8*)&Bs[(wn * 64 + j * 16 + lanelo) * 64 + co];
#pragma unroll
      for (int i = 0; i < MI; i++)
#pragma unroll
        for (int j = 0; j < 4; j++)
          acc[i][j] = __builtin_amdgcn_mfma_f32_16x16x32_bf16(af[i], bq[j], acc[i][j], 0, 0, 0);
    }
  }

  // epilogue: C/D row=(lane>>4)*4+reg, col=lane&15; reg = 4 consecutive tokens.
  int colb = n0 + wn * 64 + lanelo;
  float bvv[4];
#pragma unroll
  for (int j = 0; j < 4; j++) bvv[j] = HAS_BIAS ? bias[colb + j * 16] : 0.0f;
#pragma unroll
  for (int i = 0; i < MI; i++) {
    int r = m0 + wm * (BM / 2) + i * 16 + quad * 4;
    int bb = r >> 10, ll = r & 1023;
#pragma unroll
    for (int j = 0; j < 4; j++) {
      int c = colb + j * 16;
      float4 rv = {0.f, 0.f, 0.f, 0.f};
      if (RES_MODE == 2) rv = *(const float4*)(res + ((size_t)bb * CH + c) * SL + ll);
      float vv[4];
#pragma unroll
      for (int reg = 0; reg < 4; reg++) {
        float v = acc[i][j][reg] + bvv[j];
        if (RES_MODE == 1) v += res[(size_t)(r + reg) * N + c];
        if (RES_MODE == 2) v += (&rv.x)[reg];
        if (GELU) v = 0.5f * v * (1.0f + erff(v * 0.7071067811865476f));
        vv[reg] = v;
      }
      if (OUT_MODE & 1) {
#pragma unroll
        for (int reg = 0; reg < 4; reg++) Cf[(size_t)(r + reg) * N + c] = vv[reg];
      }
      if (OUT_MODE & 2) {
#pragma unroll
        for (int reg = 0; reg < 4; reg++) Cb[(size_t)(r + reg) * N + c] = (short)f2bf_u(vv[reg]);
      }
      if (OUT_MODE & 4) {
        float4 ov = {vv[0], vv[1], vv[2], vv[3]};
        *(float4*)(Ct + ((size_t)bb * CH + c) * SL + ll) = ov;
      }
      if (OUT_MODE & 8) {
        int part = c / 384;
        int rem = c - part * 384;
        int hh = rem / 48, dd = rem - hh * 48;
        short* dst = Chm + (size_t)part * HMS +
                     ((size_t)(bb * NHEAD + hh) * SL + ll) * 48 + dd;
#pragma unroll
        for (int reg = 0; reg < 4; reg++) dst[reg * 48] = (short)f2bf_u(vv[reg]);
      }
    }
  }
}

// ---------------- MFMA flash attention, head-major K/V, LDS bias band ----
// qh,kh,vh: (B*NH, SL, 48) bf16. ao: (NTOK, 384) bf16 token-major.
// Block: one (b,h), 128 q-rows, 4 waves x 32 rows. m-tiles of 64 keys.
// Direct global->LDS staging (round-7 structure; round-8 reg-prefetch regressed).
// Bias: needed values form a contiguous band rbh[m - l + 1056] ->
// 1152 floats staged to LDS once; in-loop reads are ds_read_b32.
__global__ __launch_bounds__(256) void k_attn_mfma(
    const short* __restrict__ qh, const short* __restrict__ kh,
    const short* __restrict__ vh, const float* __restrict__ rel_bias,
    short* __restrict__ ao) {
  __shared__ short QP[128 * 72];     // Q tile (prologue) / P patches (loop)
  __shared__ short Ks[64 * 72];
  __shared__ short Vts[48 * 72];     // transposed: row=d, col=m
  __shared__ float Bb[1152];         // bias band

  int b = blockIdx.z, h = blockIdx.y;
  int l0 = blockIdx.x * 128;
  int tid = threadIdx.x;
  int wid = tid >> 6, lane = tid & 63;
  int lanelo = lane & 15, quad = lane >> 4;
  size_t hb = ((size_t)b * NHEAD + h) * SL;
  size_t bSL = (size_t)b * SL;
  const short* kbase = kh + hb * 48;
  const short* vbase = vh + hb * 48;

  // ---- stage Q tile (contiguous 12 KB, 768 granules, 3/thread) ----
  {
    const short* qsrc = qh + (hb + l0) * 48;
#pragma unroll
    for (int s = 0; s < 3; s++) {
      int g = tid + 256 * s;
      int row = g / 6, pos = g - row * 6;
      *(uint4*)&QP[row * 72 + pos * 8] = *(const uint4*)(qsrc + g * 8);
    }
  }
  // ---- stage bias band: rbh[929-l0 .. 2080-l0] (always within [0,NBIAS)) ----
  {
    const float* bsrc = rel_bias + h * NBIAS + (929 - l0);
    for (int j = tid; j < 1152; j += 256) Bb[j] = bsrc[j];
  }
  // zero pads (Q 128 rows, K 64 rows; cols 48..63)
  for (int z = tid; z < 128 * 8; z += 256) {
    int r = z >> 3, u = z & 7;
    ((unsigned*)&QP[r * 72 + 48])[u] = 0u;
    if (r < 64) ((unsigned*)&Ks[r * 72 + 48])[u] = 0u;
  }
  __syncthreads();

  // resident Q A-fragments: [i][khalf]
  bf16x8 aq[2][2];
#pragma unroll
  for (int i = 0; i < 2; i++) {
    aq[i][0] = *(const bf16x8*)&QP[(wid * 32 + i * 16 + lanelo) * 72 + quad * 8];
    aq[i][1] = *(const bf16x8*)&QP[(wid * 32 + i * 16 + lanelo) * 72 + 32 + quad * 8];
  }

  floatx4 O[2][3];
#pragma unroll
  for (int i = 0; i < 2; i++)
#pragma unroll
    for (int d = 0; d < 3; d++) O[i][d] = {0.f, 0.f, 0.f, 0.f};
  float lsum[2][4] = {{0.f, 0.f, 0.f, 0.f}, {0.f, 0.f, 0.f, 0.f}};
  // LDS-band offset: Bb[j], j = m - (l - l0) + 127
  int boffL[2];
#pragma unroll
  for (int i = 0; i < 2; i++)
    boffL[i] = 127 - (wid * 32 + i * 16 + quad * 4) + lanelo;

  // staging assignment (tid<192): K granule pair kg=2*tid; V token-pair+d-group
  int kg = 2 * tid;
  int krow = kg / 6, kpos = kg - krow * 6;  // kg even -> kpos in {0,2,4}
  int vmp = tid & 31, vdg = tid >> 5;

  short* Pw = &QP[wid * 32 * 72];

  for (int mt = 0; mt < SL; mt += 64) {
    __syncthreads();  // previous tile's LDS readers done
    if (tid < 192) {  // direct staging (global -> reg -> LDS, same instr window)
      const short* ksrc = kbase + (size_t)mt * 48 + kg * 8;
      *(uint4*)&Ks[krow * 72 + kpos * 8] = *(const uint4*)(ksrc);
      *(uint4*)&Ks[krow * 72 + (kpos + 1) * 8] = *(const uint4*)(ksrc + 8);
      const short* vs = vbase + (size_t)(mt + 2 * vmp) * 48 + vdg * 8;
      union { uint4 u; unsigned short s[8]; } va, vb;
      va.u = *(const uint4*)vs;
      vb.u = *(const uint4*)(vs + 48);
#pragma unroll
      for (int i = 0; i < 8; i++) {
        unsigned pk = (unsigned)va.s[i] | ((unsigned)vb.s[i] << 16);
        *(unsigned*)&Vts[(vdg * 8 + i) * 72 + 2 * vmp] = pk;
      }
    }
    __syncthreads();  // tile visible

    // K B-fragments (shared across both i)
    bf16x8 kb[4][2];
#pragma unroll
    for (int nt = 0; nt < 4; nt++) {
      kb[nt][0] = *(const bf16x8*)&Ks[(nt * 16 + lanelo) * 72 + quad * 8];
      kb[nt][1] = *(const bf16x8*)&Ks[(nt * 16 + lanelo) * 72 + 32 + quad * 8];
    }

#pragma unroll
    for (int i = 0; i < 2; i++) {
      floatx4 s[4];
#pragma unroll
      for (int nt = 0; nt < 4; nt++) {
        floatx4 a = {0.f, 0.f, 0.f, 0.f};
        a = __builtin_amdgcn_mfma_f32_16x16x32_bf16(aq[i][0], kb[nt][0], a, 0, 0, 0);
        a = __builtin_amdgcn_mfma_f32_16x16x32_bf16(aq[i][1], kb[nt][1], a, 0, 0, 0);
        s[nt] = a;
      }
#pragma unroll
      for (int nt = 0; nt < 4; nt++) {
        int mo = mt + nt * 16;
#pragma unroll
        for (int reg = 0; reg < 4; reg++) {
          float e = __expf(s[nt][reg] + Bb[boffL[i] - reg + mo]);
          lsum[i][reg] += e;
          Pw[(i * 16 + quad * 4 + reg) * 72 + nt * 16 + lanelo] = (short)f2bf_u(e);
        }
      }
    }
    __asm__ volatile("s_waitcnt lgkmcnt(0)" ::: "memory");  // wave-local patch
    bf16x8 pa[2][2];
#pragma unroll
    for (int i = 0; i < 2; i++) {
      pa[i][0] = *(const bf16x8*)&Pw[(i * 16 + lanelo) * 72 + quad * 8];
      pa[i][1] = *(const bf16x8*)&Pw[(i * 16 + lanelo) * 72 + 32 + quad * 8];
    }
#pragma unroll
    for (int d = 0; d < 3; d++) {
      bf16x8 v0 = *(const bf16x8*)&Vts[(d * 16 + lanelo) * 72 + quad * 8];
      bf16x8 v1 = *(const bf16x8*)&Vts[(d * 16 + lanelo) * 72 + 32 + quad * 8];
#pragma unroll
      for (int i = 0; i < 2; i++) {
        O[i][d] = __builtin_amdgcn_mfma_f32_16x16x32_bf16(pa[i][0], v0, O[i][d], 0, 0, 0);
        O[i][d] = __builtin_amdgcn_mfma_f32_16x16x32_bf16(pa[i][1], v1, O[i][d], 0, 0, 0);
      }
    }
  }

  // ---- epilogue: row-sum reduce, normalize, store bf16 token-major ----
#pragma unroll
  for (int i = 0; i < 2; i++)
#pragma unroll
    for (int reg = 0; reg < 4; reg++) {
      float s = lsum[i][reg];
      s += __shfl_xor(s, 1, 64);
      s += __shfl_xor(s, 2, 64);
      s += __shfl_xor(s, 4, 64);
      s += __shfl_xor(s, 8, 64);
      float inv = 1.0f / s;
      size_t base =
          (bSL + (size_t)(l0 + wid * 32 + i * 16 + quad * 4 + reg)) * CH + h * DH;
      ao[base + 0 + lanelo]  = (short)f2bf_u(O[i][0][reg] * inv);
      ao[base + 16 + lanelo] = (short)f2bf_u(O[i][1][reg] * inv);
      ao[base + 32 + lanelo] = (short)f2bf_u(O[i][2][reg] * inv);
    }
}

// ---------------- launch ----------------
extern "C" void kernel_launch(void* const* d_in, const int* in_sizes, int n_in,
                              void* d_out, int out_size, void* d_ws, size_t ws_size,
                              hipStream_t stream) {
  const float* x = (const float*)d_in[0];
  const float* gamma = (const float*)d_in[1];
  const float* beta = (const float*)d_in[2];
  const float* Wq = (const float*)d_in[3];
  const float* Wk = (const float*)d_in[4];
  const float* Wv = (const float*)d_in[5];
  const float* Wo = (const float*)d_in[6];
  const float* bo = (const float*)d_in[7];
  const float* rel_bias = (const float*)d_in[8];
  const float* fc1_w = (const float*)d_in[9];
  const float* fc1_b = (const float*)d_in[10];
  const float* fc2_w = (const float*)d_in[11];
  const float* fc2_b = (const float*)d_in[12];
  float* out = (float*)d_out;

  const size_t TOKCH = (size_t)NTOK * CH;
  float* ws_f = (float*)d_ws;
  float* yb = ws_f;                            // fp32 y = x + attn-proj (token-major)
  short* wbf    = (short*)(yb + TOKCH);        // bf16 weight pool
  short* tok_bf = wbf + WTOT;                  // (NTOK, 384)
  short* hm     = tok_bf + TOKCH;              // q|k|v head-major, 3*HMS shorts
  short* ao_bf  = hm + 3 * (size_t)HMS;        // (NTOK, 384)
  short* yb_bf  = ao_bf + TOKCH;               // (NTOK, 384)
  short* h1_bf  = yb_bf + TOKCH;               // (NTOK, 1536)

  k_w2bf<<<WTOT / 8 / 256, 256, 0, stream>>>(Wq, Wk, Wv, Wo, fc1_w, fc2_w, wbf);
  k_ln_fused<<<dim3(SL / 32, BATCH), 256, 0, stream>>>(x, gamma, beta, tok_bf);

  // qkv = tok @ [Wq|Wk|Wv]^T  -> head-major q,k,v
  k_gemm_mfma<128, false, false, 0, 8>
      <<<dim3(QKVLD / 128, NTOK / 128), 256, 0, stream>>>(
          tok_bf, wbf + WQKV_OFF, nullptr, nullptr, nullptr, nullptr, nullptr,
          hm, QKVLD, CH);

  k_attn_mfma<<<dim3(SL / 128, NHEAD, BATCH), 256, 0, stream>>>(
      hm, hm + HMS, hm + 2 * (size_t)HMS, rel_bias, ao_bf);

  // y = x + ao @ Wo^T + bo  (residual from x in (B,C,L)) -> yb fp32 + bf16
  k_gemm_mfma<64, false, true, 2, 3>
      <<<dim3(CH / 128, NTOK / 64), 256, 0, stream>>>(
          ao_bf, wbf + WO_OFF, bo, x, yb, yb_bf, nullptr, nullptr, CH, CH);

  // h1 = gelu(y @ fc1_w^T + fc1_b) -> bf16
  k_gemm_mfma<128, true, true, 0, 2>
      <<<dim3(CFF / 128, NTOK / 128), 256, 0, stream>>>(
          yb_bf, wbf + F1_OFF, fc1_b, nullptr, nullptr, h1_bf, nullptr, nullptr,
          CFF, CH);

  // out(B,C,L) = y + (h1 @ fc2_w^T + fc2_b)   [direct transposed store]
  k_gemm_mfma<64, false, true, 1, 4>
      <<<dim3(CH / 128, NTOK / 64), 256, 0, stream>>>(
          h1_bf, wbf + F2_OFF, fc2_b, yb, nullptr, nullptr, out, nullptr, CH, CFF);
}